// Round 1
// baseline (496.830 us; speedup 1.0000x reference)
//
#include <hip/hip_runtime.h>

typedef __attribute__((ext_vector_type(8))) short short8;
typedef __attribute__((ext_vector_type(4))) float f32x4;

__device__ __forceinline__ float bf2f(unsigned short u){
  return __uint_as_float(((unsigned int)u) << 16);
}
__device__ __forceinline__ unsigned short f2bf(float f){
  unsigned int u = __float_as_uint(f);
  u += 0x7fffu + ((u >> 16) & 1u);   // RNE
  return (unsigned short)(u >> 16);
}
// dtype-dispatching scalar load: isF32 ? f32[i] : bf16[i]
__device__ __forceinline__ float ldf(const void* p, long i, int isF32){
  return isF32 ? ((const float*)p)[i] : bf2f(((const unsigned short*)p)[i]);
}

// ---- prep: dtype detect (block 0) + row_ptr from sorted rows ----
__global__ void prep_k(const int* __restrict__ rows, int* __restrict__ rs,
                       int E, int N, const unsigned short* __restrict__ x,
                       int* __restrict__ flag){
  if (blockIdx.x == 0){
    __shared__ int s;
    if (threadIdx.x == 0) s = 0;
    __syncthreads();
    int bad = 0;
    for (int i = threadIdx.x; i < 2048; i += 256){
      unsigned int e = ((unsigned int)x[2 * i] >> 7) & 0xffu;
      if (e >= 0xF0u) bad = 1;
    }
    if (bad) atomicOr(&s, 1);
    __syncthreads();
    if (threadIdx.x == 0) *flag = s;
  }
  int e = blockIdx.x * 256 + threadIdx.x;
  if (e >= E) return;
  if (e == 0){
    for (int r = 0; r <= rows[0]; ++r) rs[r] = 0;
  } else {
    int a = rows[e - 1], b = rows[e];
    for (int r = a + 1; r <= b; ++r) rs[r] = e;
  }
  if (e == E - 1){
    for (int r = rows[E - 1] + 1; r <= N; ++r) rs[r] = E;
  }
}

// ---- fused transpose of all three W matrices -> canonical bf16 WT ----
// blocks [0,128): Wres K=256; [128,256): W1 K=256; [256,320): W2 K=128
__global__ void wtrans_all(const void* __restrict__ Wres,
                           const void* __restrict__ W1,
                           const void* __restrict__ W2,
                           unsigned short* __restrict__ WresT,
                           unsigned short* __restrict__ W1T,
                           unsigned short* __restrict__ W2T,
                           const int* __restrict__ flag){
  int isF32 = *flag;
  int b = blockIdx.x;
  const void* W; unsigned short* WT; int K; int idx;
  if (b < 128)      { W = Wres; WT = WresT; K = 256; idx = b * 256 + threadIdx.x; }
  else if (b < 256) { W = W1;   WT = W1T;   K = 256; idx = (b - 128) * 256 + threadIdx.x; }
  else              { W = W2;   WT = W2T;   K = 128; idx = (b - 256) * 256 + threadIdx.x; }
  if (idx >= K * 128) return;
  int n = idx / K, k = idx - n * K;
  WT[idx] = f2bf(ldf(W, (long)k * 128 + n, isF32));
}

// ---- out[M][128] = A[M][K] @ W[K][128] (+bias), canonical bf16 out ----
template<int K>
__global__ __launch_bounds__(256) void gemm_bf16(
    const void* __restrict__ A,
    const unsigned short* __restrict__ WT,   // [128][K] bf16 (n-major)
    const void* __restrict__ bias,           // [128] or nullptr
    unsigned short* __restrict__ out,        // [M][128] bf16
    int M, const int* __restrict__ flagp, int aFollowsFlag)
{
  constexpr int KB = 128;
  constexpr int KP = KB + 8;
  __shared__ __align__(16) unsigned short lW[128 * KP];

  const int fl   = *flagp;
  const int aF32 = aFollowsFlag ? fl : 0;
  const int tid  = threadIdx.x;
  const int lane = tid & 63;
  const int wav  = tid >> 6;
  const int l16  = lane & 15;
  const int quad = lane >> 4;
  const int rowBase = blockIdx.x * 128 + wav * 32;

  f32x4 acc[2][8];
#pragma unroll
  for (int s = 0; s < 2; ++s)
#pragma unroll
    for (int nt = 0; nt < 8; ++nt) acc[s][nt] = (f32x4){0.f, 0.f, 0.f, 0.f};

  for (int kb = 0; kb < K; kb += KB){
    __syncthreads();
#pragma unroll
    for (int i = tid; i < 128 * KB / 8; i += 256){
      int n = i >> 4;
      int c = i & 15;
      *(short8*)&lW[n * KP + c * 8] = *(const short8*)&WT[n * K + kb + c * 8];
    }
    __syncthreads();
#pragma unroll
    for (int k0 = 0; k0 < KB; k0 += 32){
      short8 aF[2];
#pragma unroll
      for (int s = 0; s < 2; ++s){
        int r = rowBase + s * 16 + l16;
        short8 v = {};
        if (r < M){
          long off = (long)r * K + kb + k0 + quad * 8;
          if (aF32){
            const float* Af = (const float*)A + off;
            f32x4 p0 = *(const f32x4*)Af;
            f32x4 p1 = *(const f32x4*)(Af + 4);
            v[0] = (short)f2bf(p0[0]); v[1] = (short)f2bf(p0[1]);
            v[2] = (short)f2bf(p0[2]); v[3] = (short)f2bf(p0[3]);
            v[4] = (short)f2bf(p1[0]); v[5] = (short)f2bf(p1[1]);
            v[6] = (short)f2bf(p1[2]); v[7] = (short)f2bf(p1[3]);
          } else {
            v = *(const short8*)((const unsigned short*)A + off);
          }
        }
        aF[s] = v;
      }
#pragma unroll
      for (int nt = 0; nt < 8; ++nt){
        short8 bF = *(const short8*)&lW[(nt * 16 + l16) * KP + k0 + quad * 8];
        acc[0][nt] = __builtin_amdgcn_mfma_f32_16x16x32_bf16(aF[0], bF, acc[0][nt], 0, 0, 0);
        acc[1][nt] = __builtin_amdgcn_mfma_f32_16x16x32_bf16(aF[1], bF, acc[1][nt], 0, 0, 0);
      }
    }
  }

#pragma unroll
  for (int s = 0; s < 2; ++s){
    int r0 = rowBase + s * 16 + quad * 4;
#pragma unroll
    for (int nt = 0; nt < 8; ++nt){
      int col = nt * 16 + l16;
      float bv = bias ? ldf(bias, col, fl) : 0.0f;
#pragma unroll
      for (int rg = 0; rg < 4; ++rg){
        int r = r0 + rg;
        if (r < M) out[(long)r * 128 + col] = f2bf(acc[s][nt][rg] + bv);
      }
    }
  }
}

// ---- dual-output GEMM: blockIdx.y=0 -> out0 = A@W0 + bias0 (z branch),
//                        blockIdx.y=1 -> out1 = A@W1 (y1 branch).
// Reads A once through L2/L3 instead of two dispatches.
template<int K>
__global__ __launch_bounds__(256) void gemm_dual(
    const void* __restrict__ A,
    const unsigned short* __restrict__ WT0,
    const unsigned short* __restrict__ WT1,
    const void* __restrict__ bias0,
    unsigned short* __restrict__ out0,
    unsigned short* __restrict__ out1,
    int M, const int* __restrict__ flagp)
{
  constexpr int KB = 128;
  constexpr int KP = KB + 8;
  __shared__ __align__(16) unsigned short lW[128 * KP];

  const unsigned short* WT = blockIdx.y ? WT1 : WT0;
  const void* bias         = blockIdx.y ? nullptr : bias0;
  unsigned short* out      = blockIdx.y ? out1 : out0;

  const int fl   = *flagp;
  const int aF32 = fl;
  const int tid  = threadIdx.x;
  const int lane = tid & 63;
  const int wav  = tid >> 6;
  const int l16  = lane & 15;
  const int quad = lane >> 4;
  const int rowBase = blockIdx.x * 128 + wav * 32;

  f32x4 acc[2][8];
#pragma unroll
  for (int s = 0; s < 2; ++s)
#pragma unroll
    for (int nt = 0; nt < 8; ++nt) acc[s][nt] = (f32x4){0.f, 0.f, 0.f, 0.f};

  for (int kb = 0; kb < K; kb += KB){
    __syncthreads();
#pragma unroll
    for (int i = tid; i < 128 * KB / 8; i += 256){
      int n = i >> 4;
      int c = i & 15;
      *(short8*)&lW[n * KP + c * 8] = *(const short8*)&WT[n * K + kb + c * 8];
    }
    __syncthreads();
#pragma unroll
    for (int k0 = 0; k0 < KB; k0 += 32){
      short8 aF[2];
#pragma unroll
      for (int s = 0; s < 2; ++s){
        int r = rowBase + s * 16 + l16;
        short8 v = {};
        if (r < M){
          long off = (long)r * K + kb + k0 + quad * 8;
          if (aF32){
            const float* Af = (const float*)A + off;
            f32x4 p0 = *(const f32x4*)Af;
            f32x4 p1 = *(const f32x4*)(Af + 4);
            v[0] = (short)f2bf(p0[0]); v[1] = (short)f2bf(p0[1]);
            v[2] = (short)f2bf(p0[2]); v[3] = (short)f2bf(p0[3]);
            v[4] = (short)f2bf(p1[0]); v[5] = (short)f2bf(p1[1]);
            v[6] = (short)f2bf(p1[2]); v[7] = (short)f2bf(p1[3]);
          } else {
            v = *(const short8*)((const unsigned short*)A + off);
          }
        }
        aF[s] = v;
      }
#pragma unroll
      for (int nt = 0; nt < 8; ++nt){
        short8 bF = *(const short8*)&lW[(nt * 16 + l16) * KP + k0 + quad * 8];
        acc[0][nt] = __builtin_amdgcn_mfma_f32_16x16x32_bf16(aF[0], bF, acc[0][nt], 0, 0, 0);
        acc[1][nt] = __builtin_amdgcn_mfma_f32_16x16x32_bf16(aF[1], bF, acc[1][nt], 0, 0, 0);
      }
    }
  }

#pragma unroll
  for (int s = 0; s < 2; ++s){
    int r0 = rowBase + s * 16 + quad * 4;
#pragma unroll
    for (int nt = 0; nt < 8; ++nt){
      int col = nt * 16 + l16;
      float bv = bias ? ldf(bias, col, fl) : 0.0f;
#pragma unroll
      for (int rg = 0; rg < 4; ++rg){
        int r = r0 + rg;
        if (r < M) out[(long)r * 128 + col] = f2bf(acc[s][nt][rg] + bv);
      }
    }
  }
}

// ---- row-parallel gather accumulate, 8-deep MLP, clamped full-width tail ----
// All 8 gathers of a chunk are in flight before the FMA chain; tail lanes
// clamp to the last edge (same cache line, val=0) so MLP never drops.
template<int FL>
__device__ __forceinline__ void row_gather8(
    int e0, int e1, const int* __restrict__ cols, const void* __restrict__ vals,
    const unsigned short* __restrict__ Y, int lane,
    float& outx, float& outy)
{
  float ax0 = 0.f, ay0 = 0.f, ax1 = 0.f, ay1 = 0.f;
  float ax2 = 0.f, ay2 = 0.f, ax3 = 0.f, ay3 = 0.f;
  const int e1m1 = e1 - 1;
  for (int eb = e0; eb < e1; eb += 8){
    int cc[8]; float vv[8];
#pragma unroll
    for (int i = 0; i < 8; ++i){
      int e  = eb + i;
      int ec = e < e1m1 ? e : e1m1;          // clamp: stays in-row
      cc[i]  = cols[ec];
      float v = FL ? ((const float*)vals)[ec]
                   : bf2f(((const unsigned short*)vals)[ec]);
      vv[i]  = (e < e1) ? v : 0.f;           // padded lanes contribute 0
    }
    unsigned int q[8];
#pragma unroll
    for (int i = 0; i < 8; ++i)
      q[i] = *(const unsigned int*)&Y[(long)cc[i] * 128 + 2 * lane];
    ax0 = fmaf(vv[0], bf2f((unsigned short)(q[0] & 0xffffu)), ax0);
    ay0 = fmaf(vv[0], bf2f((unsigned short)(q[0] >> 16)),     ay0);
    ax1 = fmaf(vv[1], bf2f((unsigned short)(q[1] & 0xffffu)), ax1);
    ay1 = fmaf(vv[1], bf2f((unsigned short)(q[1] >> 16)),     ay1);
    ax2 = fmaf(vv[2], bf2f((unsigned short)(q[2] & 0xffffu)), ax2);
    ay2 = fmaf(vv[2], bf2f((unsigned short)(q[2] >> 16)),     ay2);
    ax3 = fmaf(vv[3], bf2f((unsigned short)(q[3] & 0xffffu)), ax3);
    ay3 = fmaf(vv[3], bf2f((unsigned short)(q[3] >> 16)),     ay3);
    ax0 = fmaf(vv[4], bf2f((unsigned short)(q[4] & 0xffffu)), ax0);
    ay0 = fmaf(vv[4], bf2f((unsigned short)(q[4] >> 16)),     ay0);
    ax1 = fmaf(vv[5], bf2f((unsigned short)(q[5] & 0xffffu)), ax1);
    ay1 = fmaf(vv[5], bf2f((unsigned short)(q[5] >> 16)),     ay1);
    ax2 = fmaf(vv[6], bf2f((unsigned short)(q[6] & 0xffffu)), ax2);
    ay2 = fmaf(vv[6], bf2f((unsigned short)(q[6] >> 16)),     ay2);
    ax3 = fmaf(vv[7], bf2f((unsigned short)(q[7] & 0xffffu)), ax3);
    ay3 = fmaf(vv[7], bf2f((unsigned short)(q[7] >> 16)),     ay3);
  }
  outx = (ax0 + ax1) + (ax2 + ax3);
  outy = (ay0 + ay1) + (ay2 + ay3);
}

// ---- spmm1 fused: x1[r] = relu(spmm(y1)[r] + b1) + z[r], bf16 out ----
__global__ __launch_bounds__(256) void spmm1_f(
    const int* __restrict__ rs, const int* __restrict__ cols,
    const void* __restrict__ vals, const unsigned short* __restrict__ Y,
    const unsigned short* __restrict__ z, const void* __restrict__ b1,
    unsigned short* __restrict__ x1, int N, const int* __restrict__ flagp)
{
  const int fl   = *flagp;
  const int lane = threadIdx.x & 63;
  const int wav  = threadIdx.x >> 6;
  int r = blockIdx.x * 4 + wav;
  if (r >= N) return;
  int e0 = __builtin_amdgcn_readfirstlane(rs[r]);
  int e1 = __builtin_amdgcn_readfirstlane(rs[r + 1]);
  float ax, ay;
  if (fl) row_gather8<1>(e0, e1, cols, vals, Y, lane, ax, ay);
  else    row_gather8<0>(e0, e1, cols, vals, Y, lane, ax, ay);
  long o = (long)r * 128 + 2 * lane;
  float b0 = ldf(b1, 2 * lane, fl), b1v = ldf(b1, 2 * lane + 1, fl);
  unsigned int zz = *(const unsigned int*)&z[o];
  float r0 = fmaxf(ax + b0,  0.f) + bf2f((unsigned short)(zz & 0xffffu));
  float r1 = fmaxf(ay + b1v, 0.f) + bf2f((unsigned short)(zz >> 16));
  *(unsigned int*)&x1[o] = (unsigned int)f2bf(r0) | ((unsigned int)f2bf(r1) << 16);
}

// ---- spmm2 fused: out[r] = log_softmax(spmm(y2)[r] + b2), dtype per flag ----
__global__ __launch_bounds__(256) void spmm2_f(
    const int* __restrict__ rs, const int* __restrict__ cols,
    const void* __restrict__ vals, const unsigned short* __restrict__ Y,
    const void* __restrict__ b2, void* __restrict__ out, int N,
    const int* __restrict__ flagp)
{
  const int fl   = *flagp;
  const int lane = threadIdx.x & 63;
  const int wav  = threadIdx.x >> 6;
  int r = blockIdx.x * 4 + wav;
  if (r >= N) return;
  int e0 = __builtin_amdgcn_readfirstlane(rs[r]);
  int e1 = __builtin_amdgcn_readfirstlane(rs[r + 1]);
  float ax, ay;
  if (fl) row_gather8<1>(e0, e1, cols, vals, Y, lane, ax, ay);
  else    row_gather8<0>(e0, e1, cols, vals, Y, lane, ax, ay);
  float v0 = ax + ldf(b2, 2 * lane, fl);
  float v1 = ay + ldf(b2, 2 * lane + 1, fl);
  float m = fmaxf(v0, v1);
#pragma unroll
  for (int off = 32; off; off >>= 1) m = fmaxf(m, __shfl_xor(m, off));
  float s = expf(v0 - m) + expf(v1 - m);
#pragma unroll
  for (int off = 32; off; off >>= 1) s += __shfl_xor(s, off);
  float lse = m + logf(s);
  long o = (long)r * 128 + 2 * lane;
  if (fl){
    float2 w; w.x = v0 - lse; w.y = v1 - lse;
    *(float2*)&((float*)out)[o] = w;
  } else {
    *(unsigned int*)&((unsigned short*)out)[o] =
        (unsigned int)f2bf(v0 - lse) | ((unsigned int)f2bf(v1 - lse) << 16);
  }
}

extern "C" void kernel_launch(void* const* d_in, const int* in_sizes, int n_in,
                              void* d_out, int out_size, void* d_ws, size_t ws_size,
                              hipStream_t stream)
{
  const void* x    = d_in[0];
  const int*  erow = (const int*)d_in[1];
  const int*  ecol = (const int*)d_in[2];
  const void* eval = d_in[3];
  const void* Wres = d_in[4];
  const void* bres = d_in[5];
  const void* W1   = d_in[6];
  const void* b1   = d_in[7];
  const void* W2   = d_in[8];
  const void* b2   = d_in[9];
  const int N = in_sizes[0] / 256;   // 100000
  const int E = in_sizes[1];         // 1600000

  char* ws = (char*)d_ws;
  size_t szB = (size_t)N * 128 * 2;  // one bf16 [N,128] plane (25.6 MB)
  unsigned short* bufA  = (unsigned short*)ws;            // y1, then y2
  unsigned short* bufC  = (unsigned short*)(ws + szB);    // x1
  unsigned short* WresT = (unsigned short*)(ws + 2 * szB);
  unsigned short* W1T   = WresT + 256 * 128;
  unsigned short* W2T   = W1T   + 256 * 128;
  int*            flag  = (int*)(W2T + 256 * 128);
  int*            rs    = flag + 4;                        // [N+1] row_ptr
  unsigned short* zbuf  = (unsigned short*)d_out;          // z (bf16) in d_out

  prep_k<<<(E + 255) / 256, 256, 0, stream>>>(erow, rs, E, N,
                                              (const unsigned short*)x, flag);
  wtrans_all<<<320, 256, 0, stream>>>(Wres, W1, W2, WresT, W1T, W2T, flag);

  const int gBlocks = (N + 127) / 128;
  const int rBlocks = (N + 3) / 4;

  dim3 gDual(gBlocks, 2);
  gemm_dual<256><<<gDual, 256, 0, stream>>>(x, WresT, W1T, bres, zbuf, bufA, N, flag); // z + y1

  spmm1_f<<<rBlocks, 256, 0, stream>>>(rs, ecol, eval, bufA, zbuf, b1, bufC, N, flag); // x1

  gemm_bf16<128><<<gBlocks, 256, 0, stream>>>(bufC, W2T, nullptr, bufA, N, flag, 0);   // y2

  spmm2_f<<<rBlocks, 256, 0, stream>>>(rs, ecol, eval, bufA, b2, d_out, N, flag);      // out
}

// Round 2
// 406.979 us; speedup vs baseline: 1.2208x; 1.2208x over previous
//
#include <hip/hip_runtime.h>

typedef __attribute__((ext_vector_type(8))) short short8;
typedef __attribute__((ext_vector_type(4))) float f32x4;

__device__ __forceinline__ float bf2f(unsigned short u){
  return __uint_as_float(((unsigned int)u) << 16);
}
__device__ __forceinline__ unsigned short f2bf(float f){
  unsigned int u = __float_as_uint(f);
  u += 0x7fffu + ((u >> 16) & 1u);   // RNE
  return (unsigned short)(u >> 16);
}
// dtype-dispatching scalar load: isF32 ? f32[i] : bf16[i]
__device__ __forceinline__ float ldf(const void* p, long i, int isF32){
  return isF32 ? ((const float*)p)[i] : bf2f(((const unsigned short*)p)[i]);
}

// ---- prep: dtype detect (block 0) + row_ptr from sorted rows ----
__global__ void prep_k(const int* __restrict__ rows, int* __restrict__ rs,
                       int E, int N, const unsigned short* __restrict__ x,
                       int* __restrict__ flag){
  if (blockIdx.x == 0){
    __shared__ int s;
    if (threadIdx.x == 0) s = 0;
    __syncthreads();
    int bad = 0;
    for (int i = threadIdx.x; i < 2048; i += 256){
      unsigned int e = ((unsigned int)x[2 * i] >> 7) & 0xffu;
      if (e >= 0xF0u) bad = 1;
    }
    if (bad) atomicOr(&s, 1);
    __syncthreads();
    if (threadIdx.x == 0) *flag = s;
  }
  int e = blockIdx.x * 256 + threadIdx.x;
  if (e >= E) return;
  if (e == 0){
    for (int r = 0; r <= rows[0]; ++r) rs[r] = 0;
  } else {
    int a = rows[e - 1], b = rows[e];
    for (int r = a + 1; r <= b; ++r) rs[r] = e;
  }
  if (e == E - 1){
    for (int r = rows[E - 1] + 1; r <= N; ++r) rs[r] = E;
  }
}

// ---- fused transpose of all three W matrices -> canonical bf16 WT ----
__global__ void wtrans_all(const void* __restrict__ Wres,
                           const void* __restrict__ W1,
                           const void* __restrict__ W2,
                           unsigned short* __restrict__ WresT,
                           unsigned short* __restrict__ W1T,
                           unsigned short* __restrict__ W2T,
                           const int* __restrict__ flag){
  int isF32 = *flag;
  int b = blockIdx.x;
  const void* W; unsigned short* WT; int K; int idx;
  if (b < 128)      { W = Wres; WT = WresT; K = 256; idx = b * 256 + threadIdx.x; }
  else if (b < 256) { W = W1;   WT = W1T;   K = 256; idx = (b - 128) * 256 + threadIdx.x; }
  else              { W = W2;   WT = W2T;   K = 128; idx = (b - 256) * 256 + threadIdx.x; }
  if (idx >= K * 128) return;
  int n = idx / K, k = idx - n * K;
  WT[idx] = f2bf(ldf(W, (long)k * 128 + n, isF32));
}

// ============================================================
// Fused dual GEMM: z = x@Wres + bres, y1 = x@W1, one A-read.
// A fragments batch-loaded (MLP 16) then MFMA'd vs BOTH W tiles.
// LDS: two 128x128 bf16 tiles, XOR-16B swizzle (64 KB exactly).
// ============================================================
__global__ __launch_bounds__(256, 2) void gemm_zy1(
    const void* __restrict__ A,
    const unsigned short* __restrict__ WT0,  // WresT [128][256]
    const unsigned short* __restrict__ WT1,  // W1T   [128][256]
    const void* __restrict__ bias0,
    unsigned short* __restrict__ out0,       // z
    unsigned short* __restrict__ out1,       // y1
    int M, const int* __restrict__ flagp)
{
  constexpr int K = 256, KB = 128;
  __shared__ __align__(16) unsigned short lW[2 * 128 * 128];  // 64 KB

  const int fl   = *flagp;
  const int tid  = threadIdx.x;
  const int lane = tid & 63;
  const int wav  = tid >> 6;
  const int l16  = lane & 15;
  const int quad = lane >> 4;
  const int rowBase = blockIdx.x * 128 + wav * 32;

  f32x4 acc[2][2][8];   // [w][s][nt]
#pragma unroll
  for (int w = 0; w < 2; ++w)
#pragma unroll
    for (int s = 0; s < 2; ++s)
#pragma unroll
      for (int nt = 0; nt < 8; ++nt) acc[w][s][nt] = (f32x4){0.f, 0.f, 0.f, 0.f};

  for (int kb = 0; kb < K; kb += KB){
    __syncthreads();   // previous-iter readers done
    // stage both W tiles: 2 * 2048 chunks of 8 shorts, swizzled
#pragma unroll
    for (int i = tid; i < 2 * 128 * 16; i += 256){
      int t = i >> 11;
      int j = i & 2047;
      int n = j >> 4;
      int c = j & 15;
      const unsigned short* WT = t ? WT1 : WT0;
      *(short8*)&lW[(t * 128 + n) * 128 + ((c * 8) ^ ((n & 7) * 8))] =
          *(const short8*)&WT[n * K + kb + c * 8];
    }
    // batched A-fragment loads for this K-half
    short8 af[2][4];
    if (fl){
#pragma unroll
      for (int s = 0; s < 2; ++s){
        int r = rowBase + s * 16 + l16;
        const float* Af = (const float*)A + (long)r * K + kb + quad * 8;
        f32x4 t0[4], t1[4];
#pragma unroll
        for (int q = 0; q < 4; ++q){
          if (r < M){
            t0[q] = *(const f32x4*)(Af + q * 32);
            t1[q] = *(const f32x4*)(Af + q * 32 + 4);
          } else {
            t0[q] = (f32x4){0.f, 0.f, 0.f, 0.f};
            t1[q] = (f32x4){0.f, 0.f, 0.f, 0.f};
          }
        }
#pragma unroll
        for (int q = 0; q < 4; ++q){
          short8 v;
          v[0] = (short)f2bf(t0[q][0]); v[1] = (short)f2bf(t0[q][1]);
          v[2] = (short)f2bf(t0[q][2]); v[3] = (short)f2bf(t0[q][3]);
          v[4] = (short)f2bf(t1[q][0]); v[5] = (short)f2bf(t1[q][1]);
          v[6] = (short)f2bf(t1[q][2]); v[7] = (short)f2bf(t1[q][3]);
          af[s][q] = v;
        }
      }
    } else {
#pragma unroll
      for (int s = 0; s < 2; ++s){
        int r = rowBase + s * 16 + l16;
        const unsigned short* Ab = (const unsigned short*)A + (long)r * K + kb + quad * 8;
#pragma unroll
        for (int q = 0; q < 4; ++q){
          short8 v = {};
          if (r < M) v = *(const short8*)(Ab + q * 32);
          af[s][q] = v;
        }
      }
    }
    __syncthreads();   // staging + A loads drained
#pragma unroll
    for (int q = 0; q < 4; ++q){
#pragma unroll
      for (int nt = 0; nt < 8; ++nt){
        int row = nt * 16 + l16;
        int bo  = row * 128 + ((q * 32 + quad * 8) ^ ((row & 7) * 8));
        short8 b0 = *(const short8*)&lW[bo];
        short8 b1 = *(const short8*)&lW[128 * 128 + bo];
        acc[0][0][nt] = __builtin_amdgcn_mfma_f32_16x16x32_bf16(af[0][q], b0, acc[0][0][nt], 0, 0, 0);
        acc[0][1][nt] = __builtin_amdgcn_mfma_f32_16x16x32_bf16(af[1][q], b0, acc[0][1][nt], 0, 0, 0);
        acc[1][0][nt] = __builtin_amdgcn_mfma_f32_16x16x32_bf16(af[0][q], b1, acc[1][0][nt], 0, 0, 0);
        acc[1][1][nt] = __builtin_amdgcn_mfma_f32_16x16x32_bf16(af[1][q], b1, acc[1][1][nt], 0, 0, 0);
      }
    }
  }

#pragma unroll
  for (int w = 0; w < 2; ++w){
    unsigned short* out = w ? out1 : out0;
#pragma unroll
    for (int s = 0; s < 2; ++s){
      int r0 = rowBase + s * 16 + quad * 4;
#pragma unroll
      for (int nt = 0; nt < 8; ++nt){
        int col = nt * 16 + l16;
        float bv = (w == 0) ? ldf(bias0, col, fl) : 0.0f;
#pragma unroll
        for (int rg = 0; rg < 4; ++rg){
          int r = r0 + rg;
          if (r < M) out[(long)r * 128 + col] = f2bf(acc[w][s][nt][rg] + bv);
        }
      }
    }
  }
}

// ============================================================
// y2 GEMM: out = A(bf16)@W2, K=128 single tile, batched A loads.
// ============================================================
__global__ __launch_bounds__(256, 3) void gemm_y2(
    const unsigned short* __restrict__ A,    // x1 bf16 [M][128]
    const unsigned short* __restrict__ WT,   // W2T [128][128]
    unsigned short* __restrict__ out,
    int M)
{
  constexpr int K = 128;
  __shared__ __align__(16) unsigned short lW[128 * 128];   // 32 KB

  const int tid  = threadIdx.x;
  const int lane = tid & 63;
  const int wav  = tid >> 6;
  const int l16  = lane & 15;
  const int quad = lane >> 4;
  const int rowBase = blockIdx.x * 128 + wav * 32;

#pragma unroll
  for (int i = tid; i < 128 * 16; i += 256){
    int n = i >> 4;
    int c = i & 15;
    *(short8*)&lW[n * 128 + ((c * 8) ^ ((n & 7) * 8))] = *(const short8*)&WT[n * K + c * 8];
  }
  short8 af[2][4];
#pragma unroll
  for (int s = 0; s < 2; ++s){
    int r = rowBase + s * 16 + l16;
    const unsigned short* Ab = A + (long)r * K + quad * 8;
#pragma unroll
    for (int q = 0; q < 4; ++q){
      short8 v = {};
      if (r < M) v = *(const short8*)(Ab + q * 32);
      af[s][q] = v;
    }
  }
  f32x4 acc[2][8];
#pragma unroll
  for (int s = 0; s < 2; ++s)
#pragma unroll
    for (int nt = 0; nt < 8; ++nt) acc[s][nt] = (f32x4){0.f, 0.f, 0.f, 0.f};
  __syncthreads();
#pragma unroll
  for (int q = 0; q < 4; ++q){
#pragma unroll
    for (int nt = 0; nt < 8; ++nt){
      int row = nt * 16 + l16;
      short8 b = *(const short8*)&lW[row * 128 + ((q * 32 + quad * 8) ^ ((row & 7) * 8))];
      acc[0][nt] = __builtin_amdgcn_mfma_f32_16x16x32_bf16(af[0][q], b, acc[0][nt], 0, 0, 0);
      acc[1][nt] = __builtin_amdgcn_mfma_f32_16x16x32_bf16(af[1][q], b, acc[1][nt], 0, 0, 0);
    }
  }
#pragma unroll
  for (int s = 0; s < 2; ++s){
    int r0 = rowBase + s * 16 + quad * 4;
#pragma unroll
    for (int nt = 0; nt < 8; ++nt){
      int col = nt * 16 + l16;
#pragma unroll
      for (int rg = 0; rg < 4; ++rg){
        int r = r0 + rg;
        if (r < M) out[(long)r * 128 + col] = f2bf(acc[s][nt][rg]);
      }
    }
  }
}

// ============================================================
// Dual-row gather: two independent edge chains interleaved per
// wave -> 16 gathers in flight. Clamped full-width tails.
// ============================================================
template<int FL>
__device__ __forceinline__ void row_gather8x2(
    int e0a, int e1a, int e0b, int e1b,
    const int* __restrict__ cols, const void* __restrict__ vals,
    const unsigned short* __restrict__ Y, int lane,
    float& oxa, float& oya, float& oxb, float& oyb)
{
  float axa0 = 0.f, aya0 = 0.f, axa1 = 0.f, aya1 = 0.f;
  float axb0 = 0.f, ayb0 = 0.f, axb1 = 0.f, ayb1 = 0.f;
  int na = e1a - e0a, nb = e1b - e0b;
  int nmax = na > nb ? na : nb;
  const int ca1 = e1a - 1, cb1 = e1b - 1;
  for (int base = 0; base < nmax; base += 8){
    int cca[8], ccb[8]; float vva[8], vvb[8];
#pragma unroll
    for (int i = 0; i < 8; ++i){
      int ea = e0a + base + i;
      int ec = ea < ca1 ? ea : ca1; ec = ec > 0 ? ec : 0;
      cca[i] = cols[ec];
      float v = FL ? ((const float*)vals)[ec]
                   : bf2f(((const unsigned short*)vals)[ec]);
      vva[i] = (ea < e1a) ? v : 0.f;
      int eb = e0b + base + i;
      int ed = eb < cb1 ? eb : cb1; ed = ed > 0 ? ed : 0;
      ccb[i] = cols[ed];
      float w = FL ? ((const float*)vals)[ed]
                   : bf2f(((const unsigned short*)vals)[ed]);
      vvb[i] = (eb < e1b) ? w : 0.f;
    }
    unsigned int qa[8], qb[8];
#pragma unroll
    for (int i = 0; i < 8; ++i){
      qa[i] = *(const unsigned int*)&Y[(long)cca[i] * 128 + 2 * lane];
      qb[i] = *(const unsigned int*)&Y[(long)ccb[i] * 128 + 2 * lane];
    }
#pragma unroll
    for (int i = 0; i < 8; ++i){
      float ylA = bf2f((unsigned short)(qa[i] & 0xffffu));
      float yhA = bf2f((unsigned short)(qa[i] >> 16));
      float ylB = bf2f((unsigned short)(qb[i] & 0xffffu));
      float yhB = bf2f((unsigned short)(qb[i] >> 16));
      if (i & 1){
        axa1 = fmaf(vva[i], ylA, axa1); aya1 = fmaf(vva[i], yhA, aya1);
        axb1 = fmaf(vvb[i], ylB, axb1); ayb1 = fmaf(vvb[i], yhB, ayb1);
      } else {
        axa0 = fmaf(vva[i], ylA, axa0); aya0 = fmaf(vva[i], yhA, aya0);
        axb0 = fmaf(vvb[i], ylB, axb0); ayb0 = fmaf(vvb[i], yhB, ayb0);
      }
    }
  }
  oxa = axa0 + axa1; oya = aya0 + aya1;
  oxb = axb0 + axb1; oyb = ayb0 + ayb1;
}

// ---- spmm1 fused: x1[r] = relu(spmm(y1)[r] + b1) + z[r], 2 rows/wave ----
__global__ __launch_bounds__(256) void spmm1_f(
    const int* __restrict__ rs, const int* __restrict__ cols,
    const void* __restrict__ vals, const unsigned short* __restrict__ Y,
    const unsigned short* __restrict__ z, const void* __restrict__ b1,
    unsigned short* __restrict__ x1, int N, const int* __restrict__ flagp)
{
  const int fl   = *flagp;
  const int lane = threadIdx.x & 63;
  const int wav  = threadIdx.x >> 6;
  int ra = blockIdx.x * 8 + wav * 2;
  if (ra >= N) return;
  int rb = ra + 1;
  bool hasB = rb < N;
  int e0a = __builtin_amdgcn_readfirstlane(rs[ra]);
  int e1a = __builtin_amdgcn_readfirstlane(rs[ra + 1]);
  int e0b = e1a, e1b = e1a;
  if (hasB) e1b = __builtin_amdgcn_readfirstlane(rs[rb + 1]);
  float axa, aya, axb, ayb;
  if (fl) row_gather8x2<1>(e0a, e1a, e0b, e1b, cols, vals, Y, lane, axa, aya, axb, ayb);
  else    row_gather8x2<0>(e0a, e1a, e0b, e1b, cols, vals, Y, lane, axa, aya, axb, ayb);
  float b0 = ldf(b1, 2 * lane, fl), b1v = ldf(b1, 2 * lane + 1, fl);
  long oa = (long)ra * 128 + 2 * lane;
  unsigned int za = *(const unsigned int*)&z[oa];
  float r0 = fmaxf(axa + b0,  0.f) + bf2f((unsigned short)(za & 0xffffu));
  float r1 = fmaxf(aya + b1v, 0.f) + bf2f((unsigned short)(za >> 16));
  *(unsigned int*)&x1[oa] = (unsigned int)f2bf(r0) | ((unsigned int)f2bf(r1) << 16);
  if (hasB){
    long ob = oa + 128;
    unsigned int zb = *(const unsigned int*)&z[ob];
    float s0 = fmaxf(axb + b0,  0.f) + bf2f((unsigned short)(zb & 0xffffu));
    float s1 = fmaxf(ayb + b1v, 0.f) + bf2f((unsigned short)(zb >> 16));
    *(unsigned int*)&x1[ob] = (unsigned int)f2bf(s0) | ((unsigned int)f2bf(s1) << 16);
  }
}

// ---- spmm2 fused: out[r] = log_softmax(spmm(y2)[r] + b2), 2 rows/wave ----
__global__ __launch_bounds__(256) void spmm2_f(
    const int* __restrict__ rs, const int* __restrict__ cols,
    const void* __restrict__ vals, const unsigned short* __restrict__ Y,
    const void* __restrict__ b2, void* __restrict__ out, int N,
    const int* __restrict__ flagp)
{
  const int fl   = *flagp;
  const int lane = threadIdx.x & 63;
  const int wav  = threadIdx.x >> 6;
  int ra = blockIdx.x * 8 + wav * 2;
  if (ra >= N) return;
  int rb = ra + 1;
  bool hasB = rb < N;
  int e0a = __builtin_amdgcn_readfirstlane(rs[ra]);
  int e1a = __builtin_amdgcn_readfirstlane(rs[ra + 1]);
  int e0b = e1a, e1b = e1a;
  if (hasB) e1b = __builtin_amdgcn_readfirstlane(rs[rb + 1]);
  float axa, aya, axb, ayb;
  if (fl) row_gather8x2<1>(e0a, e1a, e0b, e1b, cols, vals, Y, lane, axa, aya, axb, ayb);
  else    row_gather8x2<0>(e0a, e1a, e0b, e1b, cols, vals, Y, lane, axa, aya, axb, ayb);
  float bb0 = ldf(b2, 2 * lane, fl), bb1 = ldf(b2, 2 * lane + 1, fl);
  float v0a = axa + bb0, v1a = aya + bb1;
  float v0b = axb + bb0, v1b = ayb + bb1;
  float ma = fmaxf(v0a, v1a), mb = fmaxf(v0b, v1b);
#pragma unroll
  for (int off = 32; off; off >>= 1){
    ma = fmaxf(ma, __shfl_xor(ma, off));
    mb = fmaxf(mb, __shfl_xor(mb, off));
  }
  float sa = expf(v0a - ma) + expf(v1a - ma);
  float sb = expf(v0b - mb) + expf(v1b - mb);
#pragma unroll
  for (int off = 32; off; off >>= 1){
    sa += __shfl_xor(sa, off);
    sb += __shfl_xor(sb, off);
  }
  float lsea = ma + logf(sa);
  float lseb = mb + logf(sb);
  long oa = (long)ra * 128 + 2 * lane;
  if (fl){
    float2 wa; wa.x = v0a - lsea; wa.y = v1a - lsea;
    *(float2*)&((float*)out)[oa] = wa;
    if (hasB){
      float2 wb; wb.x = v0b - lseb; wb.y = v1b - lseb;
      *(float2*)&((float*)out)[oa + 128] = wb;
    }
  } else {
    *(unsigned int*)&((unsigned short*)out)[oa] =
        (unsigned int)f2bf(v0a - lsea) | ((unsigned int)f2bf(v1a - lsea) << 16);
    if (hasB){
      *(unsigned int*)&((unsigned short*)out)[oa + 128] =
          (unsigned int)f2bf(v0b - lseb) | ((unsigned int)f2bf(v1b - lseb) << 16);
    }
  }
}

extern "C" void kernel_launch(void* const* d_in, const int* in_sizes, int n_in,
                              void* d_out, int out_size, void* d_ws, size_t ws_size,
                              hipStream_t stream)
{
  const void* x    = d_in[0];
  const int*  erow = (const int*)d_in[1];
  const int*  ecol = (const int*)d_in[2];
  const void* eval = d_in[3];
  const void* Wres = d_in[4];
  const void* bres = d_in[5];
  const void* W1   = d_in[6];
  const void* b1   = d_in[7];
  const void* W2   = d_in[8];
  const void* b2   = d_in[9];
  const int N = in_sizes[0] / 256;   // 100000
  const int E = in_sizes[1];         // 1600000

  char* ws = (char*)d_ws;
  size_t szB = (size_t)N * 128 * 2;  // one bf16 [N,128] plane (25.6 MB)
  unsigned short* bufA  = (unsigned short*)ws;            // y1, then y2
  unsigned short* bufC  = (unsigned short*)(ws + szB);    // x1
  unsigned short* WresT = (unsigned short*)(ws + 2 * szB);
  unsigned short* W1T   = WresT + 256 * 128;
  unsigned short* W2T   = W1T   + 256 * 128;
  int*            flag  = (int*)(W2T + 256 * 128);
  int*            rs    = flag + 4;                        // [N+1] row_ptr
  unsigned short* zbuf  = (unsigned short*)d_out;          // z (bf16) in d_out

  prep_k<<<(E + 255) / 256, 256, 0, stream>>>(erow, rs, E, N,
                                              (const unsigned short*)x, flag);
  wtrans_all<<<320, 256, 0, stream>>>(Wres, W1, W2, WresT, W1T, W2T, flag);

  const int gBlocks = (N + 127) / 128;
  const int rBlocks = (N + 7) / 8;

  gemm_zy1<<<gBlocks, 256, 0, stream>>>(x, WresT, W1T, bres, zbuf, bufA, N, flag); // z + y1

  spmm1_f<<<rBlocks, 256, 0, stream>>>(rs, ecol, eval, bufA, zbuf, b1, bufC, N, flag); // x1

  gemm_y2<<<gBlocks, 256, 0, stream>>>(bufC, W2T, bufA, N);                            // y2

  spmm2_f<<<rBlocks, 256, 0, stream>>>(rs, ecol, eval, bufA, b2, d_out, N, flag);      // out
}